// Round 7
// baseline (304.523 us; speedup 1.0000x reference)
//
#include <hip/hip_runtime.h>
#include <math.h>

// ProbAttention (Informer ProbSparse) — B=8 L=2048 H=8 D=64 u=40
// q/k/v reshape(B,H,L,D) is a flat reinterpretation -> treat as (BH=64, L, D) contiguous.
#define LSEQ 2048
#define DDIM 64
#define UU   40
#define NBH  64
#define NCHUNK 16
#define CROWS  128            // rows per k-chunk (CROWS*NCHUNK == LSEQ)
#define CTX_ELEMS (NBH*UU*DDIM)   // 163840

// 8-lane-group sum via DPP (pure VALU — keeps the LDS pipe free for k-row reads).
__device__ __forceinline__ float grp8_sum(float x) {
  float t;
  t = __int_as_float(__builtin_amdgcn_update_dpp(0, __float_as_int(x), 0xB1, 0xF, 0xF, false));
  x += t;
  t = __int_as_float(__builtin_amdgcn_update_dpp(0, __float_as_int(x), 0x4E, 0xF, 0xF, false));
  x += t;
  t = __int_as_float(__builtin_amdgcn_update_dpp(0, __float_as_int(x), 0x141, 0xF, 0xF, false));
  x += t;
  return x;
}

// ---------------- K0a: bin sample indices by 128-row chunk (shared across all bh) ---
// One wave per l. Stable wave-parallel bucket sort via ballot/popcount. [proven R2-R6]
__global__ __launch_bounds__(256) void k0_sort(
    const int* __restrict__ idxs, int* __restrict__ sidx, int* __restrict__ soff) {
  int l = blockIdx.x * 4 + (threadIdx.x >> 6);
  int lane = threadIdx.x & 63;
  int v = 0, c = NCHUNK;              // lanes >= UU get invalid chunk
  if (lane < UU) { v = idxs[l * UU + lane]; c = v >> 7; }   // 128 rows/chunk
  unsigned long long lower = (1ull << lane) - 1ull;
  int base = 0;
#pragma unroll
  for (int cc = 0; cc < NCHUNK; ++cc) {
    unsigned long long m = __ballot(c == cc);
    if (c == cc) {
      int rank = __popcll(m & lower);
      sidx[l * UU + base + rank] = v;
    }
    int cnt = __popcll(m);
    if (lane == cc) soff[l * NCHUNK + cc] = (base << 8) | cnt;
    base += cnt;
  }
}

// ---------------- K0b: per chunk, counting-sort l's by cnt (descending) -------------
// R6 diagnosis: k12 is issue-bound and ~55% of slot issues are exec-masked waste
// because a wave's 8 groups have cnt ~ Binomial(40,1/16) and the slot loop runs to
// the wave max (~5.5 vs mean 2.5). Sorting l's by cnt makes adjacent 8-tuples
// near-equal (max ~= mean) and clusters cnt=0 l's at the tail. 16 tiny blocks.
__global__ __launch_bounds__(256) void k0_order(
    const int* __restrict__ soff, int* __restrict__ order) {
  int c = blockIdx.x;
  int t = threadIdx.x;
  __shared__ int hist[48];
  __shared__ int pos[48];
  if (t < 48) hist[t] = 0;
  __syncthreads();
  int cl[8];
#pragma unroll
  for (int j = 0; j < 8; ++j) {
    int l = t + 256 * j;
    cl[j] = soff[l * NCHUNK + c] & 255;
    atomicAdd(&hist[cl[j]], 1);
  }
  __syncthreads();
  if (t == 0) {                       // 41-bin serial prefix, descending cnt
    int run = 0;
    for (int x = 40; x >= 0; --x) { pos[x] = run; run += hist[x]; }
  }
  __syncthreads();
#pragma unroll
  for (int j = 0; j < 8; ++j) {
    int p = atomicAdd(&pos[cl[j]], 1);
    order[c * LSEQ + p] = t + 256 * j;    // any order within equal cnt is valid
  }
}

// ---------------- K12 v9: LDS-chunk gather, cnt-balanced batches -------------------
// 1024 blocks (bh = b&63, c = b>>6), 512 threads (8 waves), 32KB LDS, 4 blocks/CU.
// Wave-batch = 8 adjacent entries of order[c] -> near-equal cnt -> executed slots
// ~= mean (2.8) instead of wave-max (5.5). cnt==0 groups (sorted to the tail) skip
// q/sidx loads and all slots; they only write Mpart(-INF,0) (k3's fmax handles it —
// every l has >=1 nonempty chunk since 40 samples exist).
// k read from HBM exactly once (32MB). q re-reads stay XCD-L2-local (bh%8 == b%8).
__global__ __launch_bounds__(512, 8) void k12_gather(
    const float* __restrict__ q, const float* __restrict__ k,
    const int* __restrict__ sidx, const int* __restrict__ soff,
    const int* __restrict__ order, float2* __restrict__ Mpart) {
  __shared__ float4 kt[CROWS * 16];   // 32KB, linear row-major
  int b = blockIdx.x;
  int bh = b & 63;
  int c  = b >> 6;
  int t  = threadIdx.x;

  {
    const float4* src = (const float4*)(k + ((size_t)bh * LSEQ + c * CROWS) * DDIM);
#pragma unroll
    for (int j = 0; j < 4; ++j) kt[t + 512 * j] = src[t + 512 * j];
  }
  __syncthreads();

  int w = t >> 6;            // wave 0..7 owns order positions [w*256, w*256+256)
  int lane = t & 63;
  int g = lane >> 3;         // group 0..7 (one l each per batch)
  int sub = lane & 7;

#pragma unroll 1
  for (int lb = 0; lb < 256; lb += 8) {
    int l = order[c * LSEQ + w * 256 + lb + g];   // group-uniform broadcast load
    int oc   = soff[l * NCHUNK + c];
    int cnt  = oc & 255;
    int base = oc >> 8;
    float4 qa = make_float4(0.f, 0.f, 0.f, 0.f), qb = qa;
    int rowv[8] = {0, 0, 0, 0, 0, 0, 0, 0};
    if (cnt > 0) {
      const float4* qr = (const float4*)(q + ((size_t)bh * LSEQ + l) * DDIM);
      qa = qr[sub];           // q row bytes [0,128)
      qb = qr[sub + 8];       // q row bytes [128,256)
      const int* sp = sidx + l * UU + base;   // sidx padded +16 -> safe overread
#pragma unroll
      for (int s = 0; s < 8; ++s) rowv[s] = sp[s] & (CROWS - 1);
    }
    float mx = -INFINITY, sm = 0.f;
#pragma unroll
    for (int s = 0; s < 8; ++s) {
      if (__any(s < cnt)) {                   // near-uniform after sorting
        if (s < cnt) {
          const float4* kr = kt + rowv[s] * 16;
          float4 a  = kr[sub];
          float4 bq = kr[sub + 8];
          float d = qa.x * a.x + qa.y * a.y + qa.z * a.z + qa.w * a.w
                  + qb.x * bq.x + qb.y * bq.y + qb.z * bq.z + qb.w * bq.w;
          d = grp8_sum(d);                    // group-wide: all 8 lanes active
          mx = fmaxf(mx, d);
          sm += d;
        }
      }
    }
    for (int s = 8; s < cnt; ++s) {           // very rare (P(cnt>8) ~ 5e-4)
      int row = sidx[l * UU + base + s] & (CROWS - 1);
      const float4* kr = kt + row * 16;
      float4 a  = kr[sub];
      float4 bq = kr[sub + 8];
      float d = qa.x * a.x + qa.y * a.y + qa.z * a.z + qa.w * a.w
              + qb.x * bq.x + qb.y * bq.y + qb.z * bq.z + qb.w * bq.w;
      d = grp8_sum(d);
      mx = fmaxf(mx, d);
      sm += d;
    }
    if (sub == 0) Mpart[((size_t)bh * NCHUNK + c) * LSEQ + l] = make_float2(mx, sm);
  }
}

// ---------------- K3: top-40 per head; combines 16 Mpart chunks during load --------
// desc value, tie -> smaller index (matches jax.lax.top_k stability)
__global__ __launch_bounds__(256) void k3_topk(const float2* __restrict__ Mp,
                                               int* __restrict__ Mtop) {
  int bh = blockIdx.x;
  int t = threadIdx.x;
  int w = t >> 6;
  int lane = t & 63;
  float v[8];
#pragma unroll
  for (int j = 0; j < 8; ++j) {
    int l = t + 256 * j;
    float mxv = -INFINITY, smv = 0.f;
#pragma unroll
    for (int c = 0; c < NCHUNK; ++c) {
      float2 p = Mp[((size_t)bh * NCHUNK + c) * LSEQ + l];
      mxv = fmaxf(mxv, p.x);
      smv += p.y;
    }
    v[j] = mxv - smv * (1.0f / (float)LSEQ);
  }
  __shared__ float swv[4];
  __shared__ int   swi[4];
  __shared__ int   win;
  for (int it = 0; it < UU; ++it) {
    float bv = -INFINITY; int bi = 0x7fffffff;
#pragma unroll
    for (int j = 0; j < 8; ++j) {
      if (v[j] > bv) { bv = v[j]; bi = t + 256 * j; }
    }
#pragma unroll
    for (int off = 32; off > 0; off >>= 1) {
      float ov = __shfl_xor(bv, off, 64);
      int   oi = __shfl_xor(bi, off, 64);
      if (ov > bv || (ov == bv && oi < bi)) { bv = ov; bi = oi; }
    }
    if (lane == 0) { swv[w] = bv; swi[w] = bi; }
    __syncthreads();
    if (t == 0) {
      float fv = swv[0]; int fi = swi[0];
#pragma unroll
      for (int j = 1; j < 4; ++j) {
        if (swv[j] > fv || (swv[j] == fv && swi[j] < fi)) { fv = swv[j]; fi = swi[j]; }
      }
      Mtop[bh * UU + it] = fi;
      win = fi;
    }
    __syncthreads();
    int wi = win;
#pragma unroll
    for (int j = 0; j < 8; ++j)
      if (wi == t + 256 * j) v[j] = -INFINITY;   // static index, predicated
  }
}

// ---------------- K457: scores + softmax + CONTEXT, fully fused [proven R5] --------
// 640 blocks: bh = b&63, ug = b>>6 (4 u each). LDS = sct 32KB + vtile 16KB = 48KB
// -> 3 blocks/CU. Unchanged (one-variable discipline).
__global__ __launch_bounds__(256, 3) void k457_fused(
    const float* __restrict__ q, const float* __restrict__ k,
    const float* __restrict__ v, const int* __restrict__ Mtop,
    float* __restrict__ attn, float* __restrict__ ctx) {
  __shared__ float  sct[4 * LSEQ];     // 32KB, [u][l]: scores -> normalized attn
  __shared__ float4 vt4[64 * 16];      // 16KB v tile (swizzled); reused as pacc
  int b = blockIdx.x;
  int bh = b & 63;
  int u0 = (b >> 6) * 4;
  int t = threadIdx.x;

  // ---- phase A: scores (R0-proven 4-lane geometry) ----
  {
    int g = t >> 2;
    int sub = t & 3;
    float4 qv[4][4];
#pragma unroll
    for (int u = 0; u < 4; ++u) {
      int qi = Mtop[bh * UU + u0 + u];
      const float4* qr = (const float4*)(q + (size_t)(bh * LSEQ + qi) * DDIM);
#pragma unroll
      for (int m = 0; m < 4; ++m) qv[u][m] = qr[4 * m + sub];
    }
    const float* kb = k + (size_t)bh * LSEQ * DDIM;
#pragma unroll 1
    for (int p = 0; p < 32; ++p) {
      int l = p * 64 + g;
      const float4* kr = (const float4*)(kb + (size_t)l * DDIM);
      float4 ks[4];
#pragma unroll
      for (int m = 0; m < 4; ++m) ks[m] = kr[4 * m + sub];
      float d[4];
#pragma unroll
      for (int u = 0; u < 4; ++u) {
        float s = 0.f;
#pragma unroll
        for (int m = 0; m < 4; ++m) {
          float4 x = qv[u][m], a = ks[m];
          s += x.x * a.x + x.y * a.y + x.z * a.z + x.w * a.w;
        }
        s += __shfl_xor(s, 1, 64);
        s += __shfl_xor(s, 2, 64);
        d[u] = s * 0.125f;
      }
      if (sub == 0) {
#pragma unroll
        for (int u = 0; u < 4; ++u) sct[u * LSEQ + l] = d[u];
      }
    }
  }
  __syncthreads();

  // ---- softmax: wave w owns u-row w; write normalized to sct AND attn ----
  int w = t >> 6, lane = t & 63;
  {
    float* row = sct + w * LSEQ;
    float vv[32];
    float mx = -INFINITY;
#pragma unroll
    for (int j = 0; j < 32; ++j) { vv[j] = row[lane + 64 * j]; mx = fmaxf(mx, vv[j]); }
#pragma unroll
    for (int off = 32; off > 0; off >>= 1) mx = fmaxf(mx, __shfl_xor(mx, off, 64));
    float sm = 0.f;
#pragma unroll
    for (int j = 0; j < 32; ++j) { vv[j] = __expf(vv[j] - mx); sm += vv[j]; }
#pragma unroll
    for (int off = 32; off > 0; off >>= 1) sm += __shfl_xor(sm, off, 64);
    float inv = 1.0f / sm;
    float* ap = attn + (size_t)(bh * UU + u0 + w) * LSEQ;
#pragma unroll
    for (int j = 0; j < 32; ++j) {
      float a = vv[j] * inv;
      row[lane + 64 * j] = a;
      ap[lane + 64 * j] = a;
    }
  }
  __syncthreads();

  // ---- phase B: ctx[bh, u0+u, :] = sum_l attn[u][l] * v[bh, l, :] ----
  int dq = lane & 15;        // d-quad: d = dq*4 .. dq*4+3
  int lq = lane >> 4;        // row-slice 0..3
  float4 acc[4];
#pragma unroll
  for (int u = 0; u < 4; ++u) acc[u] = make_float4(0.f, 0.f, 0.f, 0.f);

  const float4* vsrc = (const float4*)(v + (size_t)bh * LSEQ * DDIM);
#pragma unroll 1
  for (int tile = 0; tile < 32; ++tile) {
    // stage 64 v rows, float4-slot swizzle: slot = c4 ^ (row&3)
#pragma unroll
    for (int i = 0; i < 4; ++i) {
      int idx = t + 256 * i;            // float4 index in tile (0..1023)
      int row = idx >> 4, c4 = idx & 15;
      vt4[row * 16 + (c4 ^ (row & 3))] = vsrc[tile * 1024 + idx];
    }
    __syncthreads();
#pragma unroll
    for (int i = 0; i < 4; ++i) {
      int r = w * 16 + i * 4 + lq;      // row in tile; wave w owns rows w*16..+16
      int l = tile * 64 + r;
      float4 vv4 = vt4[r * 16 + (dq ^ (r & 3))];   // 4 lq -> 4 distinct bank sets
#pragma unroll
      for (int u = 0; u < 4; ++u) {
        float a = sct[u * LSEQ + l];    // 4 distinct addrs/wave, 16-way broadcast
        acc[u].x += a * vv4.x;
        acc[u].y += a * vv4.y;
        acc[u].z += a * vv4.z;
        acc[u].w += a * vv4.w;
      }
    }
    __syncthreads();                    // protect vt4 before next stage
  }

  // reduce partials over lq (lane bits 4,5) — dq position preserved
#pragma unroll
  for (int u = 0; u < 4; ++u) {
    acc[u].x += __shfl_xor(acc[u].x, 16, 64);
    acc[u].y += __shfl_xor(acc[u].y, 16, 64);
    acc[u].z += __shfl_xor(acc[u].z, 16, 64);
    acc[u].w += __shfl_xor(acc[u].w, 16, 64);
    acc[u].x += __shfl_xor(acc[u].x, 32, 64);
    acc[u].y += __shfl_xor(acc[u].y, 32, 64);
    acc[u].z += __shfl_xor(acc[u].z, 32, 64);
    acc[u].w += __shfl_xor(acc[u].w, 32, 64);
  }
  __syncthreads();                      // vt4 free -> reuse as pacc[w][u][64]
  float* pacc = (float*)vt4;
  if (lq == 0) {
#pragma unroll
    for (int u = 0; u < 4; ++u)
      ((float4*)pacc)[(w * 4 + u) * 16 + dq] = acc[u];
  }
  __syncthreads();
  {
    int uu = t >> 6, d = t & 63;
    float s = pacc[(0 * 4 + uu) * 64 + d] + pacc[(1 * 4 + uu) * 64 + d]
            + pacc[(2 * 4 + uu) * 64 + d] + pacc[(3 * 4 + uu) * 64 + d];
    ctx[((size_t)bh * UU + u0 + uu) * DDIM + d] = s;
  }
}

extern "C" void kernel_launch(void* const* d_in, const int* in_sizes, int n_in,
                              void* d_out, int out_size, void* d_ws, size_t ws_size,
                              hipStream_t stream) {
  const float* q   = (const float*)d_in[0];
  const float* k   = (const float*)d_in[1];
  const float* v   = (const float*)d_in[2];
  const int*   idx = (const int*)d_in[3];

  float* ctx  = (float*)d_out;                  // [NBH, UU, DDIM]
  float* attn = (float*)d_out + CTX_ELEMS;      // [NBH, UU, LSEQ]
  // Mpart scratch lives in the attn output region; consumed by k3 BEFORE k457
  // overwrites the region with real attn. NBH*NCHUNK*LSEQ float2 = 4.19M floats
  // < 5.24M available. [proven R2/R4/R5/R6]
  float2* Mpart = (float2*)attn;

  int* sidx  = (int*)d_ws;                       // LSEQ*UU + 16 pad = 81936 ints
  int* soff  = sidx + LSEQ * UU + 16;            // LSEQ*NCHUNK     = 32768 ints
  int* Mtop  = soff + LSEQ * NCHUNK;             // NBH*UU          = 2560 ints
  int* order = Mtop + NBH * UU;                  // NCHUNK*LSEQ     = 32768 ints

  k0_sort<<<LSEQ / 4, 256, 0, stream>>>(idx, sidx, soff);
  k0_order<<<NCHUNK, 256, 0, stream>>>(soff, order);
  k12_gather<<<NBH * NCHUNK, 512, 0, stream>>>(q, k, sidx, soff, order, Mpart);
  k3_topk<<<NBH, 256, 0, stream>>>(Mpart, Mtop);
  k457_fused<<<NBH * 10, 256, 0, stream>>>(q, k, v, Mtop, attn, ctx);
}

// Round 8
// 301.132 us; speedup vs baseline: 1.0113x; 1.0113x over previous
//
#include <hip/hip_runtime.h>
#include <math.h>

// ProbAttention (Informer ProbSparse) — B=8 L=2048 H=8 D=64 u=40
// q/k/v reshape(B,H,L,D) is a flat reinterpretation -> treat as (BH=64, L, D) contiguous.
#define LSEQ 2048
#define DDIM 64
#define UU   40
#define NBH  64
#define NCHUNK 16
#define CROWS  128            // rows per k-chunk (CROWS*NCHUNK == LSEQ)
#define CTX_ELEMS (NBH*UU*DDIM)   // 163840

// 8-lane-group sum via DPP (pure VALU — keeps the LDS pipe free for k-row reads).
__device__ __forceinline__ float grp8_sum(float x) {
  float t;
  t = __int_as_float(__builtin_amdgcn_update_dpp(0, __float_as_int(x), 0xB1, 0xF, 0xF, false));
  x += t;
  t = __int_as_float(__builtin_amdgcn_update_dpp(0, __float_as_int(x), 0x4E, 0xF, 0xF, false));
  x += t;
  t = __int_as_float(__builtin_amdgcn_update_dpp(0, __float_as_int(x), 0x141, 0xF, 0xF, false));
  x += t;
  return x;
}

// ---------------- K0a: bin sample indices by 128-row chunk (shared across all bh) ---
// One wave per l. Stable wave-parallel bucket sort via ballot/popcount. [proven R2-R7]
__global__ __launch_bounds__(256) void k0_sort(
    const int* __restrict__ idxs, int* __restrict__ sidx, int* __restrict__ soff) {
  int l = blockIdx.x * 4 + (threadIdx.x >> 6);
  int lane = threadIdx.x & 63;
  int v = 0, c = NCHUNK;              // lanes >= UU get invalid chunk
  if (lane < UU) { v = idxs[l * UU + lane]; c = v >> 7; }   // 128 rows/chunk
  unsigned long long lower = (1ull << lane) - 1ull;
  int base = 0;
#pragma unroll
  for (int cc = 0; cc < NCHUNK; ++cc) {
    unsigned long long m = __ballot(c == cc);
    if (c == cc) {
      int rank = __popcll(m & lower);
      sidx[l * UU + base + rank] = v;
    }
    int cnt = __popcll(m);
    if (lane == cc) soff[l * NCHUNK + cc] = (base << 8) | cnt;
    base += cnt;
  }
}

// ---------------- K0b: SEGMENT-LOCAL counting-sort of l's by cnt (descending) -------
// R7 lesson measured both effects separately: cnt-balance saves ~15-25us of issue
// time, but GLOBAL sorting scattered q reads + Mpart writes (hbm_bytes 54->127MB,
// +40us). Fix: sort only within each wave's own 256-l segment. q stays in a 64KB
// L2-resident window, Mpart writes in a 2KB window (lines fully written while
// L2-resident -> no RMW amplification), balance nearly intact (mean 2.5, segment
// max-of-8-adjacent ~2.8 vs unsorted wave-max 5.5).
// 128 blocks = (chunk, segment); one thread per l; 41-bin counting sort.
__global__ __launch_bounds__(256) void k0_order(
    const int* __restrict__ soff, int* __restrict__ order) {
  int c   = blockIdx.x >> 3;
  int seg = blockIdx.x & 7;
  int t = threadIdx.x;
  int l = seg * 256 + t;
  __shared__ int hist[41];
  __shared__ int pos[41];
  if (t < 41) hist[t] = 0;
  __syncthreads();
  int cnt = soff[l * NCHUNK + c] & 255;
  atomicAdd(&hist[cnt], 1);
  __syncthreads();
  if (t == 0) {                       // 41-bin serial prefix, descending cnt
    int run = 0;
    for (int x = 40; x >= 0; --x) { pos[x] = run; run += hist[x]; }
  }
  __syncthreads();
  int p = atomicAdd(&pos[cnt], 1);
  order[c * LSEQ + seg * 256 + p] = l;   // stays within this wave's segment
}

// ---------------- K12 v10: LDS-chunk gather, segment-balanced batches --------------
// 1024 blocks (bh = b&63, c = b>>6), 512 threads (8 waves), 32KB LDS, 4 blocks/CU.
// Identical body to R7; only the ordering scope changed (order[] values are now
// confined to each wave's 256-l segment -> R6's memory locality + R7's balance).
// k read from HBM exactly once (32MB). q re-reads XCD-L2-local (bh%8 == b%8).
__global__ __launch_bounds__(512, 8) void k12_gather(
    const float* __restrict__ q, const float* __restrict__ k,
    const int* __restrict__ sidx, const int* __restrict__ soff,
    const int* __restrict__ order, float2* __restrict__ Mpart) {
  __shared__ float4 kt[CROWS * 16];   // 32KB, linear row-major
  int b = blockIdx.x;
  int bh = b & 63;
  int c  = b >> 6;
  int t  = threadIdx.x;

  {
    const float4* src = (const float4*)(k + ((size_t)bh * LSEQ + c * CROWS) * DDIM);
#pragma unroll
    for (int j = 0; j < 4; ++j) kt[t + 512 * j] = src[t + 512 * j];
  }
  __syncthreads();

  int w = t >> 6;            // wave 0..7 owns order positions [w*256, w*256+256)
  int lane = t & 63;
  int g = lane >> 3;         // group 0..7 (one l each per batch)
  int sub = lane & 7;

#pragma unroll 1
  for (int lb = 0; lb < 256; lb += 8) {
    int l = order[c * LSEQ + w * 256 + lb + g];   // group-uniform broadcast load
    int oc   = soff[l * NCHUNK + c];
    int cnt  = oc & 255;
    int base = oc >> 8;
    float4 qa = make_float4(0.f, 0.f, 0.f, 0.f), qb = qa;
    int rowv[8] = {0, 0, 0, 0, 0, 0, 0, 0};
    if (cnt > 0) {
      const float4* qr = (const float4*)(q + ((size_t)bh * LSEQ + l) * DDIM);
      qa = qr[sub];           // q row bytes [0,128)
      qb = qr[sub + 8];       // q row bytes [128,256)
      const int* sp = sidx + l * UU + base;   // sidx padded +16 -> safe overread
#pragma unroll
      for (int s = 0; s < 8; ++s) rowv[s] = sp[s] & (CROWS - 1);
    }
    float mx = -INFINITY, sm = 0.f;
#pragma unroll
    for (int s = 0; s < 8; ++s) {
      if (__any(s < cnt)) {                   // near-uniform after segment sort
        if (s < cnt) {
          const float4* kr = kt + rowv[s] * 16;
          float4 a  = kr[sub];
          float4 bq = kr[sub + 8];
          float d = qa.x * a.x + qa.y * a.y + qa.z * a.z + qa.w * a.w
                  + qb.x * bq.x + qb.y * bq.y + qb.z * bq.z + qb.w * bq.w;
          d = grp8_sum(d);                    // group-wide: all 8 lanes active
          mx = fmaxf(mx, d);
          sm += d;
        }
      }
    }
    for (int s = 8; s < cnt; ++s) {           // very rare (P(cnt>8) ~ 5e-4)
      int row = sidx[l * UU + base + s] & (CROWS - 1);
      const float4* kr = kt + row * 16;
      float4 a  = kr[sub];
      float4 bq = kr[sub + 8];
      float d = qa.x * a.x + qa.y * a.y + qa.z * a.z + qa.w * a.w
              + qb.x * bq.x + qb.y * bq.y + qb.z * bq.z + qb.w * bq.w;
      d = grp8_sum(d);
      mx = fmaxf(mx, d);
      sm += d;
    }
    if (sub == 0) Mpart[((size_t)bh * NCHUNK + c) * LSEQ + l] = make_float2(mx, sm);
  }
}

// ---------------- K3: top-40 per head; combines 16 Mpart chunks during load --------
// desc value, tie -> smaller index (matches jax.lax.top_k stability)
__global__ __launch_bounds__(256) void k3_topk(const float2* __restrict__ Mp,
                                               int* __restrict__ Mtop) {
  int bh = blockIdx.x;
  int t = threadIdx.x;
  int w = t >> 6;
  int lane = t & 63;
  float v[8];
#pragma unroll
  for (int j = 0; j < 8; ++j) {
    int l = t + 256 * j;
    float mxv = -INFINITY, smv = 0.f;
#pragma unroll
    for (int c = 0; c < NCHUNK; ++c) {
      float2 p = Mp[((size_t)bh * NCHUNK + c) * LSEQ + l];
      mxv = fmaxf(mxv, p.x);
      smv += p.y;
    }
    v[j] = mxv - smv * (1.0f / (float)LSEQ);
  }
  __shared__ float swv[4];
  __shared__ int   swi[4];
  __shared__ int   win;
  for (int it = 0; it < UU; ++it) {
    float bv = -INFINITY; int bi = 0x7fffffff;
#pragma unroll
    for (int j = 0; j < 8; ++j) {
      if (v[j] > bv) { bv = v[j]; bi = t + 256 * j; }
    }
#pragma unroll
    for (int off = 32; off > 0; off >>= 1) {
      float ov = __shfl_xor(bv, off, 64);
      int   oi = __shfl_xor(bi, off, 64);
      if (ov > bv || (ov == bv && oi < bi)) { bv = ov; bi = oi; }
    }
    if (lane == 0) { swv[w] = bv; swi[w] = bi; }
    __syncthreads();
    if (t == 0) {
      float fv = swv[0]; int fi = swi[0];
#pragma unroll
      for (int j = 1; j < 4; ++j) {
        if (swv[j] > fv || (swv[j] == fv && swi[j] < fi)) { fv = swv[j]; fi = swi[j]; }
      }
      Mtop[bh * UU + it] = fi;
      win = fi;
    }
    __syncthreads();
    int wi = win;
#pragma unroll
    for (int j = 0; j < 8; ++j)
      if (wi == t + 256 * j) v[j] = -INFINITY;   // static index, predicated
  }
}

// ---------------- K457: scores + softmax + CONTEXT, fully fused [proven R5] --------
// 640 blocks: bh = b&63, ug = b>>6 (4 u each). LDS = sct 32KB + vtile 16KB = 48KB
// -> 3 blocks/CU. Unchanged (one-variable discipline).
__global__ __launch_bounds__(256, 3) void k457_fused(
    const float* __restrict__ q, const float* __restrict__ k,
    const float* __restrict__ v, const int* __restrict__ Mtop,
    float* __restrict__ attn, float* __restrict__ ctx) {
  __shared__ float  sct[4 * LSEQ];     // 32KB, [u][l]: scores -> normalized attn
  __shared__ float4 vt4[64 * 16];      // 16KB v tile (swizzled); reused as pacc
  int b = blockIdx.x;
  int bh = b & 63;
  int u0 = (b >> 6) * 4;
  int t = threadIdx.x;

  // ---- phase A: scores (R0-proven 4-lane geometry) ----
  {
    int g = t >> 2;
    int sub = t & 3;
    float4 qv[4][4];
#pragma unroll
    for (int u = 0; u < 4; ++u) {
      int qi = Mtop[bh * UU + u0 + u];
      const float4* qr = (const float4*)(q + (size_t)(bh * LSEQ + qi) * DDIM);
#pragma unroll
      for (int m = 0; m < 4; ++m) qv[u][m] = qr[4 * m + sub];
    }
    const float* kb = k + (size_t)bh * LSEQ * DDIM;
#pragma unroll 1
    for (int p = 0; p < 32; ++p) {
      int l = p * 64 + g;
      const float4* kr = (const float4*)(kb + (size_t)l * DDIM);
      float4 ks[4];
#pragma unroll
      for (int m = 0; m < 4; ++m) ks[m] = kr[4 * m + sub];
      float d[4];
#pragma unroll
      for (int u = 0; u < 4; ++u) {
        float s = 0.f;
#pragma unroll
        for (int m = 0; m < 4; ++m) {
          float4 x = qv[u][m], a = ks[m];
          s += x.x * a.x + x.y * a.y + x.z * a.z + x.w * a.w;
        }
        s += __shfl_xor(s, 1, 64);
        s += __shfl_xor(s, 2, 64);
        d[u] = s * 0.125f;
      }
      if (sub == 0) {
#pragma unroll
        for (int u = 0; u < 4; ++u) sct[u * LSEQ + l] = d[u];
      }
    }
  }
  __syncthreads();

  // ---- softmax: wave w owns u-row w; write normalized to sct AND attn ----
  int w = t >> 6, lane = t & 63;
  {
    float* row = sct + w * LSEQ;
    float vv[32];
    float mx = -INFINITY;
#pragma unroll
    for (int j = 0; j < 32; ++j) { vv[j] = row[lane + 64 * j]; mx = fmaxf(mx, vv[j]); }
#pragma unroll
    for (int off = 32; off > 0; off >>= 1) mx = fmaxf(mx, __shfl_xor(mx, off, 64));
    float sm = 0.f;
#pragma unroll
    for (int j = 0; j < 32; ++j) { vv[j] = __expf(vv[j] - mx); sm += vv[j]; }
#pragma unroll
    for (int off = 32; off > 0; off >>= 1) sm += __shfl_xor(sm, off, 64);
    float inv = 1.0f / sm;
    float* ap = attn + (size_t)(bh * UU + u0 + w) * LSEQ;
#pragma unroll
    for (int j = 0; j < 32; ++j) {
      float a = vv[j] * inv;
      row[lane + 64 * j] = a;
      ap[lane + 64 * j] = a;
    }
  }
  __syncthreads();

  // ---- phase B: ctx[bh, u0+u, :] = sum_l attn[u][l] * v[bh, l, :] ----
  int dq = lane & 15;        // d-quad: d = dq*4 .. dq*4+3
  int lq = lane >> 4;        // row-slice 0..3
  float4 acc[4];
#pragma unroll
  for (int u = 0; u < 4; ++u) acc[u] = make_float4(0.f, 0.f, 0.f, 0.f);

  const float4* vsrc = (const float4*)(v + (size_t)bh * LSEQ * DDIM);
#pragma unroll 1
  for (int tile = 0; tile < 32; ++tile) {
    // stage 64 v rows, float4-slot swizzle: slot = c4 ^ (row&3)
#pragma unroll
    for (int i = 0; i < 4; ++i) {
      int idx = t + 256 * i;            // float4 index in tile (0..1023)
      int row = idx >> 4, c4 = idx & 15;
      vt4[row * 16 + (c4 ^ (row & 3))] = vsrc[tile * 1024 + idx];
    }
    __syncthreads();
#pragma unroll
    for (int i = 0; i < 4; ++i) {
      int r = w * 16 + i * 4 + lq;      // row in tile; wave w owns rows w*16..+16
      int l = tile * 64 + r;
      float4 vv4 = vt4[r * 16 + (dq ^ (r & 3))];   // 4 lq -> 4 distinct bank sets
#pragma unroll
      for (int u = 0; u < 4; ++u) {
        float a = sct[u * LSEQ + l];    // 4 distinct addrs/wave, 16-way broadcast
        acc[u].x += a * vv4.x;
        acc[u].y += a * vv4.y;
        acc[u].z += a * vv4.z;
        acc[u].w += a * vv4.w;
      }
    }
    __syncthreads();                    // protect vt4 before next stage
  }

  // reduce partials over lq (lane bits 4,5) — dq position preserved
#pragma unroll
  for (int u = 0; u < 4; ++u) {
    acc[u].x += __shfl_xor(acc[u].x, 16, 64);
    acc[u].y += __shfl_xor(acc[u].y, 16, 64);
    acc[u].z += __shfl_xor(acc[u].z, 16, 64);
    acc[u].w += __shfl_xor(acc[u].w, 16, 64);
    acc[u].x += __shfl_xor(acc[u].x, 32, 64);
    acc[u].y += __shfl_xor(acc[u].y, 32, 64);
    acc[u].z += __shfl_xor(acc[u].z, 32, 64);
    acc[u].w += __shfl_xor(acc[u].w, 32, 64);
  }
  __syncthreads();                      // vt4 free -> reuse as pacc[w][u][64]
  float* pacc = (float*)vt4;
  if (lq == 0) {
#pragma unroll
    for (int u = 0; u < 4; ++u)
      ((float4*)pacc)[(w * 4 + u) * 16 + dq] = acc[u];
  }
  __syncthreads();
  {
    int uu = t >> 6, d = t & 63;
    float s = pacc[(0 * 4 + uu) * 64 + d] + pacc[(1 * 4 + uu) * 64 + d]
            + pacc[(2 * 4 + uu) * 64 + d] + pacc[(3 * 4 + uu) * 64 + d];
    ctx[((size_t)bh * UU + u0 + uu) * DDIM + d] = s;
  }
}

extern "C" void kernel_launch(void* const* d_in, const int* in_sizes, int n_in,
                              void* d_out, int out_size, void* d_ws, size_t ws_size,
                              hipStream_t stream) {
  const float* q   = (const float*)d_in[0];
  const float* k   = (const float*)d_in[1];
  const float* v   = (const float*)d_in[2];
  const int*   idx = (const int*)d_in[3];

  float* ctx  = (float*)d_out;                  // [NBH, UU, DDIM]
  float* attn = (float*)d_out + CTX_ELEMS;      // [NBH, UU, LSEQ]
  // Mpart scratch lives in the attn output region; consumed by k3 BEFORE k457
  // overwrites the region with real attn. NBH*NCHUNK*LSEQ float2 = 4.19M floats
  // < 5.24M available. [proven R2/R4-R7]
  float2* Mpart = (float2*)attn;

  int* sidx  = (int*)d_ws;                       // LSEQ*UU + 16 pad = 81936 ints
  int* soff  = sidx + LSEQ * UU + 16;            // LSEQ*NCHUNK     = 32768 ints
  int* Mtop  = soff + LSEQ * NCHUNK;             // NBH*UU          = 2560 ints
  int* order = Mtop + NBH * UU;                  // NCHUNK*LSEQ     = 32768 ints

  k0_sort<<<LSEQ / 4, 256, 0, stream>>>(idx, sidx, soff);
  k0_order<<<NCHUNK * 8, 256, 0, stream>>>(soff, order);
  k12_gather<<<NBH * NCHUNK, 512, 0, stream>>>(q, k, sidx, soff, order, Mpart);
  k3_topk<<<NBH, 256, 0, stream>>>(Mpart, Mtop);
  k457_fused<<<NBH * 10, 256, 0, stream>>>(q, k, v, Mtop, attn, ctx);
}